// Round 6
// baseline (259.974 us; speedup 1.0000x reference)
//
#include <hip/hip_runtime.h>
#include <math.h>

#define N_NODES 50000
#define N_EDGES 800000
#define D_FEAT 128
#define HIDDEN 256
#define NB_SCAN 196           // ceil(50000/256)
#define GEMM_BLOCKS 782       // ceil(50000/64)

#define PREP_CVT_B 512
#define PREP_CNT_B 256
#define PREP_WF_B 64
#define FILL_B 512
#define AGG_B 2048            // 8192 waves

typedef __bf16 bf16x8 __attribute__((ext_vector_type(8)));
typedef float f32x4 __attribute__((ext_vector_type(4)));

__device__ __forceinline__ unsigned f2b(float f) {
    unsigned u = __builtin_bit_cast(unsigned, f);
    return (u + 0x7fff + ((u >> 16) & 1)) >> 16;  // RNE, low 16 bits valid
}

// ---------- fused prep: cvt_x | count | build_wfrag (fat grid-stride blocks) ----------
// Arow[node][128 uints]: uints 0..63 = mean (bf16x2, filled by agg1), 64..127 = x (bf16x2)
__global__ __launch_bounds__(256) void prep(
    const float* __restrict__ x, const int* __restrict__ dst,
    const float* __restrict__ W1l, const float* __restrict__ W1r,
    unsigned* __restrict__ Arow, int* __restrict__ cnt,
    unsigned short* __restrict__ Wfrag) {
    int b = blockIdx.x;
    int t = threadIdx.x;
    if (b < PREP_CVT_B) {
        // 800000 uint4 outputs (= 3.2M uints = 6.4M floats)
        for (int g = b * 256 + t; g < 800000; g += PREP_CVT_B * 256) {
            float4 v0 = *(const float4*)(x + (size_t)g * 8);
            float4 v1 = *(const float4*)(x + (size_t)g * 8 + 4);
            uint4 o;
            o.x = f2b(v0.x) | (f2b(v0.y) << 16);
            o.y = f2b(v0.z) | (f2b(v0.w) << 16);
            o.z = f2b(v1.x) | (f2b(v1.y) << 16);
            o.w = f2b(v1.z) | (f2b(v1.w) << 16);
            int d = g >> 4;
            int j = (g << 2) & 63;
            *(uint4*)(Arow + (size_t)d * 128 + 64 + j) = o;
        }
    } else if (b < PREP_CVT_B + PREP_CNT_B) {
        for (int e = (b - PREP_CVT_B) * 256 + t; e < N_EDGES; e += PREP_CNT_B * 256)
            atomicAdd(&cnt[dst[e]], 1);
    } else {
        for (int tt = (b - PREP_CVT_B - PREP_CNT_B) * 256 + t; tt < 65536;
             tt += PREP_WF_B * 256) {
            int j = tt & 7;
            int lane = (tt >> 3) & 63;
            int ks = (tt >> 9) & 7;
            int nt = tt >> 12;
            int k = ks * 32 + ((lane >> 4) << 3) + j;
            int n = (nt << 4) + (lane & 15);
            float v = (k < 128) ? W1l[k * 256 + n] : W1r[(k - 128) * 256 + n];
            Wfrag[tt] = (unsigned short)f2b(v);
        }
    }
}

// ---------- CSR scan step 1: per-block sums ----------
__global__ void scan1(const int* __restrict__ cnt, int* __restrict__ bsum) {
    __shared__ int tmp[256];
    int t = threadIdx.x;
    int i = blockIdx.x * 256 + t;
    tmp[t] = (i < N_NODES) ? cnt[i] : 0;
    __syncthreads();
    for (int off = 128; off > 0; off >>= 1) {
        if (t < off) tmp[t] += tmp[t + off];
        __syncthreads();
    }
    if (t == 0) bsum[blockIdx.x] = tmp[0];
}

// ---------- CSR scan step 2 (fused old scan2+scan3): row begin offsets ----------
__global__ void scanB(const int* __restrict__ cnt, const int* __restrict__ bsum,
                      int* __restrict__ rowpos) {
    __shared__ int bs[256];
    __shared__ int tmp[256];
    int t = threadIdx.x;
    int b = blockIdx.x;
    bs[t] = (t < NB_SCAN) ? bsum[t] : 0;
    __syncthreads();
    for (int off = 1; off < 256; off <<= 1) {
        int y = (t >= off) ? bs[t - off] : 0;
        __syncthreads();
        bs[t] += y;
        __syncthreads();
    }
    int boff = (b == 0) ? 0 : bs[b - 1];
    int i = b * 256 + t;
    int v = (i < N_NODES) ? cnt[i] : 0;
    tmp[t] = v;
    __syncthreads();
    for (int off = 1; off < 256; off <<= 1) {
        int y = (t >= off) ? tmp[t - off] : 0;
        __syncthreads();
        tmp[t] += y;
        __syncthreads();
    }
    if (i < N_NODES) rowpos[i] = tmp[t] - v + boff;  // exclusive begin
}

// after fill, rowpos[d] == end offset; beg = end - cnt[d]
__global__ __launch_bounds__(256) void fill_kernel(
    const int* __restrict__ src, const int* __restrict__ dst,
    int* __restrict__ rowpos, unsigned short* __restrict__ esrc) {
    for (int e = blockIdx.x * 256 + threadIdx.x; e < N_EDGES; e += FILL_B * 256) {
        int pos = atomicAdd(&rowpos[dst[e]], 1);
        esrc[pos] = (unsigned short)src[e];
    }
}

// ---------- agg1: wave-per-node grid-stride, gather-mean of x (bf16) -> Arow mean ----------
__global__ __launch_bounds__(256) void agg1(
    const unsigned* __restrict__ Arow_x, unsigned* __restrict__ Arow_m,
    const unsigned short* __restrict__ esrc,
    const int* __restrict__ rowend, const int* __restrict__ cnt) {
    int wid = (blockIdx.x * 256 + threadIdx.x) >> 6;   // 8192 waves
    int lane = threadIdx.x & 63;
    for (int d = wid; d < N_NODES; d += AGG_B * 4) {
        int end = rowend[d];
        int c = cnt[d];
        float a0 = 0.0f, a1 = 0.0f;
        for (int base = end - c; base < end; base += 64) {
            int m = end - base; if (m > 64) m = 64;
            int idx = base + lane;
            int e = (int)esrc[idx < end ? idx : end - 1];  // coalesced, clamped
            for (int j0 = 0; j0 < m; j0 += 8) {
#pragma unroll
                for (int j = 0; j < 8; j++) {
                    int s = __shfl(e, j0 + j);                        // broadcast
                    unsigned u = Arow_x[(size_t)s * 128 + 64 + lane]; // 2 bf16
                    float sc = (j0 + j < m) ? 1.0f : 0.0f;            // uniform mask
                    a0 += sc * __builtin_bit_cast(float, u << 16);
                    a1 += sc * __builtin_bit_cast(float, u & 0xffff0000u);
                }
            }
        }
        float inv = 1.0f / fmaxf((float)c, 1.0f);
        Arow_m[(size_t)d * 128 + lane] = f2b(a0 * inv) | (f2b(a1 * inv) << 16);
    }
}

// ---------- gemm1 + fused ps: h = relu([mean|x]@Wcat + b1); p = h@W2l; s = h@W2r + b2 ----------
__global__ __launch_bounds__(256) void gemm1ps(
    const unsigned* __restrict__ Arow, const unsigned short* __restrict__ Wfrag,
    const float* __restrict__ b1, const float* __restrict__ W2l,
    const float* __restrict__ W2r, const float* __restrict__ b2,
    float* __restrict__ h, float* __restrict__ p, float* __restrict__ s) {
    __shared__ unsigned A[64 * 128];   // 32 KB, 16B-chunk XOR swizzled
    __shared__ float ppart[64][4];     // p0,p1,s0,s1 partials per row

    int r0 = blockIdx.x * 64;
    int tid = threadIdx.x;
    int w = tid >> 6;
    int lane = tid & 63;
    int quad = lane >> 4;
    int l15 = lane & 15;

    ((float*)ppart)[tid] = 0.0f;

    int sr = tid >> 2;
    int cb = (tid & 3) << 3;
#pragma unroll
    for (int j = 0; j < 8; j++) {
        int c = cb + j;
        uint4 v = *(const uint4*)(Arow + (size_t)(r0 + sr) * 128 + (c << 2));
        int cp = c ^ (sr & 7);
        *(uint4*)(A + sr * 128 + (cp << 2)) = v;
    }
    __syncthreads();

    f32x4 acc[16];
#pragma unroll
    for (int i = 0; i < 16; i++) acc[i] = (f32x4){0.0f, 0.0f, 0.0f, 0.0f};

    for (int ks = 0; ks < 8; ks++) {
        bf16x8 bfr[4];
#pragma unroll
        for (int nt = 0; nt < 4; nt++) {
            int ntg = (w << 2) + nt;
            uint4 raw = *(const uint4*)(Wfrag + ((((ntg << 3) + ks) << 6) + lane) * 8);
            bfr[nt] = __builtin_bit_cast(bf16x8, raw);
        }
#pragma unroll
        for (int mt = 0; mt < 4; mt++) {
            int row = (mt << 4) + l15;
            int c = (ks << 2) + quad;
            uint4 araw = *(const uint4*)(A + row * 128 + ((c ^ (row & 7)) << 2));
            bf16x8 afr = __builtin_bit_cast(bf16x8, araw);
#pragma unroll
            for (int nt = 0; nt < 4; nt++) {
                acc[(mt << 2) + nt] = __builtin_amdgcn_mfma_f32_16x16x32_bf16(
                    afr, bfr[nt], acc[(mt << 2) + nt], 0, 0, 0);
            }
        }
    }

    // epilogue: relu + h store + ps partials. D layout: col=lane&15, row=quad*4+reg
    float w2[4][4];
#pragma unroll
    for (int nt = 0; nt < 4; nt++) {
        int col = (w << 6) + (nt << 4) + l15;
        float2 l2 = *(const float2*)(W2l + col * 2);
        float2 r2 = *(const float2*)(W2r + col * 2);
        w2[nt][0] = l2.x; w2[nt][1] = l2.y; w2[nt][2] = r2.x; w2[nt][3] = r2.y;
    }

#pragma unroll
    for (int mt = 0; mt < 4; mt++) {
        float red[4][4];
#pragma unroll
        for (int v = 0; v < 4; v++)
#pragma unroll
            for (int r = 0; r < 4; r++) red[v][r] = 0.0f;

#pragma unroll
        for (int nt = 0; nt < 4; nt++) {
            int col = (w << 6) + (nt << 4) + l15;
            float b = b1[col];
            f32x4 v = acc[(mt << 2) + nt];
#pragma unroll
            for (int r = 0; r < 4; r++) {
                float hv = v[r] + b;
                hv = hv > 0.0f ? hv : 0.0f;
                int row = r0 + (mt << 4) + (quad << 2) + r;
                if (row < N_NODES) h[(size_t)row * 256 + col] = hv;
                red[0][r] += hv * w2[nt][0];
                red[1][r] += hv * w2[nt][1];
                red[2][r] += hv * w2[nt][2];
                red[3][r] += hv * w2[nt][3];
            }
        }
#pragma unroll
        for (int v = 0; v < 4; v++)
#pragma unroll
            for (int r = 0; r < 4; r++) {
                red[v][r] += __shfl_xor(red[v][r], 1);
                red[v][r] += __shfl_xor(red[v][r], 2);
                red[v][r] += __shfl_xor(red[v][r], 4);
                red[v][r] += __shfl_xor(red[v][r], 8);
            }
        if (l15 == 0) {
            int lrow = (mt << 4) + (quad << 2);
#pragma unroll
            for (int r = 0; r < 4; r++)
#pragma unroll
                for (int v = 0; v < 4; v++)
                    atomicAdd(&ppart[lrow + r][v], red[v][r]);
        }
    }
    __syncthreads();

    if (tid < 64) {
        int row = r0 + tid;
        if (row < N_NODES) {
            float2 pv = {ppart[tid][0], ppart[tid][1]};
            float2 sv = {ppart[tid][2] + b2[0], ppart[tid][3] + b2[1]};
            *(float2*)(p + (size_t)row * 2) = pv;
            *(float2*)(s + (size_t)row * 2) = sv;
        }
    }
}

// ---------- layer-2: wave-per-node grid-stride, gather-mean of p + sigmoid ----------
__global__ __launch_bounds__(256) void agg2(
    const float* __restrict__ p, const float* __restrict__ s,
    const unsigned short* __restrict__ esrc,
    const int* __restrict__ rowend, const int* __restrict__ cnt,
    float* __restrict__ out) {
    int wid = (blockIdx.x * 256 + threadIdx.x) >> 6;
    int lane = threadIdx.x & 63;
    for (int d = wid; d < N_NODES; d += AGG_B * 4) {
        int end = rowend[d];
        int c = cnt[d];
        float a0 = 0.0f, a1 = 0.0f;
        for (int base = end - c; base < end; base += 64) {
            int idx = base + lane;
            if (idx < end) {
                int ss = (int)esrc[idx];
                float2 v = *(const float2*)(p + (size_t)ss * 2);
                a0 += v.x; a1 += v.y;
            }
        }
#pragma unroll
        for (int off = 32; off > 0; off >>= 1) {
            a0 += __shfl_down(a0, off);
            a1 += __shfl_down(a1, off);
        }
        if (lane == 0) {
            float inv = 1.0f / fmaxf((float)c, 1.0f);
            float z0 = a0 * inv + s[(size_t)d * 2 + 0];
            float z1 = a1 * inv + s[(size_t)d * 2 + 1];
            float2 o = {1.0f / (1.0f + expf(-z0)), 1.0f / (1.0f + expf(-z1))};
            *(float2*)(out + (size_t)d * 2) = o;
        }
    }
}

extern "C" void kernel_launch(void* const* d_in, const int* in_sizes, int n_in,
                              void* d_out, int out_size, void* d_ws, size_t ws_size,
                              hipStream_t stream) {
    const float* x   = (const float*)d_in[0];
    const int*   ei  = (const int*)d_in[1];
    const float* W1l = (const float*)d_in[2];
    const float* W1r = (const float*)d_in[3];
    const float* b1  = (const float*)d_in[4];
    const float* W2l = (const float*)d_in[5];
    const float* W2r = (const float*)d_in[6];
    const float* b2  = (const float*)d_in[7];

    const int* src = ei;
    const int* dst = ei + N_EDGES;

    float* out = (float*)d_out;               // [50000, 2]
    float* emb = out + (size_t)N_NODES * 2;   // [50000, 256] == h

    // ---- workspace layout ----
    int* cnt    = (int*)d_ws;                             // 50000
    int* rowpos = cnt + N_NODES;                          // 50000
    int* bsum   = rowpos + N_NODES;                       // 256
    unsigned short* esrc = (unsigned short*)(bsum + 256); // 800064 (16B-mult pad)
    unsigned* Arow = (unsigned*)(esrc + 800064);          // 50048 rows x 128 uints
    unsigned short* Wfrag = (unsigned short*)(Arow + (size_t)50048 * 128);  // 65536
    float* p = (float*)(Wfrag + 65536);                   // 100000
    float* s = p + (size_t)N_NODES * 2;                   // 100000

    hipMemsetAsync(cnt, 0, N_NODES * sizeof(int), stream);

    prep<<<PREP_CVT_B + PREP_CNT_B + PREP_WF_B, 256, 0, stream>>>(
        x, dst, W1l, W1r, Arow, cnt, Wfrag);

    scan1<<<NB_SCAN, 256, 0, stream>>>(cnt, bsum);
    scanB<<<NB_SCAN, 256, 0, stream>>>(cnt, bsum, rowpos);
    fill_kernel<<<FILL_B, 256, 0, stream>>>(src, dst, rowpos, esrc);

    agg1<<<AGG_B, 256, 0, stream>>>(Arow, Arow, esrc, rowpos, cnt);

    gemm1ps<<<GEMM_BLOCKS, 256, 0, stream>>>(Arow, Wfrag, b1, W2l, W2r, b2, emb, p, s);

    agg2<<<AGG_B, 256, 0, stream>>>(p, s, esrc, rowpos, cnt, out);
}